// Round 2
// baseline (2296.261 us; speedup 1.0000x reference)
//
#include <hip/hip_runtime.h>
#include <stdint.h>

#define SEQ   2048
#define NBATCH 64
#define IND   256
#define HIDN  256

using short8  = __attribute__((ext_vector_type(8))) short;
using floatx4 = __attribute__((ext_vector_type(4))) float;

__device__ __forceinline__ unsigned bf16r(float f) {
    unsigned u = __builtin_bit_cast(unsigned, f);
    return (u + 0x8000u) >> 16;   // round-half-up to bf16
}

__device__ __forceinline__ short8 pack8(floatx4 f0, floatx4 f1) {
    short8 s;
    s[0] = (short)bf16r(f0[0]); s[1] = (short)bf16r(f0[1]);
    s[2] = (short)bf16r(f0[2]); s[3] = (short)bf16r(f0[3]);
    s[4] = (short)bf16r(f1[0]); s[5] = (short)bf16r(f1[1]);
    s[6] = (short)bf16r(f1[2]); s[7] = (short)bf16r(f1[3]);
    return s;
}

// tanh(z) = 1 - 2/(1+e^{2z});  e^{2z} = exp2(z * 2/ln2).  NaN-safe at +-inf.
__device__ __forceinline__ float tanh_fast(float z) {
    float a = __builtin_amdgcn_exp2f(z * 2.8853900817779268f);
    return __builtin_fmaf(-2.0f, __builtin_amdgcn_rcpf(1.0f + a), 1.0f);
}

// CK-style LDS-only barrier: s_waitcnt lgkmcnt(0) + s_barrier via intrinsics.
// 0xc07f = vmcnt(63) expcnt(7) lgkmcnt(0) -- valid for both 4-bit and 6-bit
// lgkmcnt encodings. Unlike inline asm with a "memory" clobber, these
// intrinsics do NOT make SIInsertWaitcnts drain vmcnt(0), so the per-step
// global stores and the 2-step-deep xp prefetch stay in flight across the
// barrier (the R0->R1 1860us was dominated by that per-step vmem drain).
__device__ __forceinline__ void lds_barrier() {
    __builtin_amdgcn_s_waitcnt(0xc07f);
    __builtin_amdgcn_s_barrier();
}

// ---------------------------------------------------------------------------
// Kernel 1: x_proj[s][b][n] = sum_i input[s][b][i]*W_ih[n][i] + b_ih[n] + b_hh[n]
// stored as bf16 bits (ushort). Grid: 2048 blocks x 256 thr; 64 M-rows/block.
// ---------------------------------------------------------------------------
__global__ __launch_bounds__(256, 2) void proj_kernel(
    const float* __restrict__ inp, const float* __restrict__ W_ih,
    const float* __restrict__ b_ih, const float* __restrict__ b_hh,
    unsigned short* __restrict__ xp)
{
    const int tid  = threadIdx.x;
    const int w    = tid >> 6;          // wave 0..3 -> n-quarter
    const int lane = tid & 63;
    const int c    = lane & 15;         // lane&15: A row (m) / B col (n) / D col
    const int q    = lane >> 4;         // quad: k = q*8+j, D rows = q*4+r
    const size_t R0 = (size_t)blockIdx.x * 64;

    // B-frags: B[k][n] = W_ih[n][k]
    short8 bfr[4][8];
    float bias[4];
    #pragma unroll
    for (int tn = 0; tn < 4; ++tn) {
        const int n = 64 * w + 16 * tn + c;
        bias[tn] = b_ih[n] + b_hh[n];
        #pragma unroll
        for (int kk = 0; kk < 8; ++kk) {
            const float* p = W_ih + (size_t)n * 256 + kk * 32 + q * 8;
            bfr[tn][kk] = pack8(*(const floatx4*)p, *(const floatx4*)(p + 4));
        }
    }

    #pragma unroll
    for (int mt = 0; mt < 4; ++mt) {
        short8 afr[8];
        const float* arow = inp + (R0 + 16 * mt + c) * 256;
        #pragma unroll
        for (int kk = 0; kk < 8; ++kk) {
            const float* p = arow + kk * 32 + q * 8;
            afr[kk] = pack8(*(const floatx4*)p, *(const floatx4*)(p + 4));
        }
        floatx4 acc[4];
        #pragma unroll
        for (int tn = 0; tn < 4; ++tn) {
            floatx4 a0; a0[0] = bias[tn]; a0[1] = bias[tn]; a0[2] = bias[tn]; a0[3] = bias[tn];
            acc[tn] = a0;
        }
        #pragma unroll
        for (int kk = 0; kk < 8; ++kk)
            #pragma unroll
            for (int tn = 0; tn < 4; ++tn)
                acc[tn] = __builtin_amdgcn_mfma_f32_16x16x32_bf16(afr[kk], bfr[tn][kk], acc[tn], 0, 0, 0);
        #pragma unroll
        for (int tn = 0; tn < 4; ++tn) {
            const unsigned col = 64 * w + 16 * tn + c;
            #pragma unroll
            for (int r = 0; r < 4; ++r) {
                const size_t row = R0 + 16 * mt + q * 4 + r;
                xp[row * 256 + col] = (unsigned short)bf16r(acc[tn][r]);
            }
        }
    }
}

// ---------------------------------------------------------------------------
// Kernel 2: serial recurrence. 4 blocks x 16 batches, 4 waves/block, each wave
// owns a 64-wide hidden slice. W_hh resident in registers (bf16 B-frags); h
// double-buffered in LDS bf16, row stride 264 ushort. lds_barrier() keeps the
// global stores + 2-step xp register prefetch in flight across steps.
// MFMA loop is kk-outer so the 4 acc chains interleave (issue-bound, not
// dep-latency-bound -- only 1 wave/SIMD here, nothing else hides latency).
// ---------------------------------------------------------------------------
__global__ __launch_bounds__(256, 1) void rnn_kernel(
    const float* __restrict__ W_hh,
    const unsigned short* __restrict__ xp,   // bf16 bits [SEQ][NBATCH][HIDN]
    float* __restrict__ out)                 // fp32 [SEQ*NBATCH][HIDN]
{
    __shared__ __align__(16) unsigned short hbuf[2][16 * 264];
    const int tid  = threadIdx.x;
    const int w    = tid >> 6, lane = tid & 63;
    const int c    = lane & 15, q = lane >> 4;
    const int B0   = blockIdx.x * 16;

    // B-frags: B[k][n] = W_hh[n][k]
    short8 bfr[4][8];
    #pragma unroll
    for (int tn = 0; tn < 4; ++tn) {
        const int n = 64 * w + 16 * tn + c;
        #pragma unroll
        for (int kk = 0; kk < 8; ++kk) {
            const float* p = W_hh + (size_t)n * 256 + kk * 32 + q * 8;
            bfr[tn][kk] = pack8(*(const floatx4*)p, *(const floatx4*)(p + 4));
        }
    }

    // h0 = 0
    for (int i = tid; i < 2 * 16 * 264; i += 256) (&hbuf[0][0])[i] = 0;
    __syncthreads();

    // per-lane flat offset into [t][b][n]: b = B0+q*4+r, n = 64w+16tn+c
    const unsigned lofs = (unsigned)(B0 + q * 4) * 256 + 64 * w + c;
    const unsigned short* xq = xp + lofs;
    float* oq = out + lofs;

    // 2-deep xp prefetch ring (vals indexed i = r*4+tn)
    unsigned xa[16], xb[16];
    #pragma unroll
    for (int i = 0; i < 16; ++i) {
        const int tn = i & 3, r = i >> 2;
        xa[i] = xq[r * 256 + tn * 16];           // t = 0
        xb[i] = xq[16384 + r * 256 + tn * 16];   // t = 1
    }

    auto step = [&](int t, int sel, unsigned* xv) {
        // A-frags from LDS: A[m=c][k=kk*32+q*8+j], row stride 264 ushort
        short8 afr[8];
        #pragma unroll
        for (int kk = 0; kk < 8; ++kk)
            afr[kk] = *(const short8*)&hbuf[sel][c * 264 + kk * 32 + q * 8];

        // acc init = x_proj (consume prefetched regs; bf16 -> f32 is <<16)
        floatx4 acc[4];
        #pragma unroll
        for (int tn = 0; tn < 4; ++tn) {
            floatx4 a0;
            a0[0] = __builtin_bit_cast(float, xv[0 * 4 + tn] << 16);
            a0[1] = __builtin_bit_cast(float, xv[1 * 4 + tn] << 16);
            a0[2] = __builtin_bit_cast(float, xv[2 * 4 + tn] << 16);
            a0[3] = __builtin_bit_cast(float, xv[3 * 4 + tn] << 16);
            acc[tn] = a0;
        }

        // prefetch x_proj for t+2 (clamped; last loads are dead but in-bounds)
        {
            const int tp = (t + 2 < SEQ) ? (t + 2) : (SEQ - 1);
            const unsigned short* p = xq + (size_t)tp * 16384;
            #pragma unroll
            for (int i = 0; i < 16; ++i) {
                const int tn = i & 3, r = i >> 2;
                xv[i] = p[r * 256 + tn * 16];
            }
        }

        // kk-outer: consecutive MFMAs are independent (4 interleaved chains)
        #pragma unroll
        for (int kk = 0; kk < 8; ++kk)
            #pragma unroll
            for (int tn = 0; tn < 4; ++tn)
                acc[tn] = __builtin_amdgcn_mfma_f32_16x16x32_bf16(afr[kk], bfr[tn][kk], acc[tn], 0, 0, 0);

        // epilogue: tanh, store fp32 out, write bf16 h_new to other LDS buffer
        float* op = oq + (size_t)t * 16384;
        unsigned short* hw = &hbuf[sel ^ 1][0];
        #pragma unroll
        for (int tn = 0; tn < 4; ++tn) {
            #pragma unroll
            for (int r = 0; r < 4; ++r) {
                const float hn = tanh_fast(acc[tn][r]);
                op[r * 256 + tn * 16] = hn;
                hw[(q * 4 + r) * 264 + 64 * w + 16 * tn + c] = (unsigned short)bf16r(hn);
            }
        }
        // LDS-only barrier: vmem (stores + prefetch) stays in flight
        lds_barrier();
    };

    for (int t = 0; t < SEQ; t += 2) {
        step(t, 0, xa);
        step(t + 1, 1, xb);
    }
}

extern "C" void kernel_launch(void* const* d_in, const int* in_sizes, int n_in,
                              void* d_out, int out_size, void* d_ws, size_t ws_size,
                              hipStream_t stream) {
    const float* input = (const float*)d_in[0];
    const float* W_ih  = (const float*)d_in[1];
    const float* W_hh  = (const float*)d_in[2];
    const float* b_ih  = (const float*)d_in[3];
    const float* b_hh  = (const float*)d_in[4];
    float* out = (float*)d_out;
    unsigned short* xp = (unsigned short*)d_ws;  // 2048*64*256 bf16 = 64 MiB

    proj_kernel<<<(SEQ * NBATCH) / 64, 256, 0, stream>>>(input, W_ih, b_ih, b_hh, xp);
    rnn_kernel<<<4, 256, 0, stream>>>(W_hh, xp, out);
}

// Round 3
// 1662.448 us; speedup vs baseline: 1.3813x; 1.3813x over previous
//
#include <hip/hip_runtime.h>
#include <stdint.h>

#define SEQ   2048
#define NBATCH 64
#define IND   256
#define HIDN  256

using short8  = __attribute__((ext_vector_type(8))) short;
using floatx4 = __attribute__((ext_vector_type(4))) float;

__device__ __forceinline__ unsigned bf16r(float f) {
    unsigned u = __builtin_bit_cast(unsigned, f);
    return (u + 0x8000u) >> 16;   // round-half-up to bf16
}

__device__ __forceinline__ short8 pack8(floatx4 f0, floatx4 f1) {
    short8 s;
    s[0] = (short)bf16r(f0[0]); s[1] = (short)bf16r(f0[1]);
    s[2] = (short)bf16r(f0[2]); s[3] = (short)bf16r(f0[3]);
    s[4] = (short)bf16r(f1[0]); s[5] = (short)bf16r(f1[1]);
    s[6] = (short)bf16r(f1[2]); s[7] = (short)bf16r(f1[3]);
    return s;
}

// tanh(z) = 1 - 2/(1+e^{2z});  e^{2z} = exp2(z * 2/ln2).  NaN-safe at +-inf.
__device__ __forceinline__ float tanh_fast(float z) {
    float a = __builtin_amdgcn_exp2f(z * 2.8853900817779268f);
    return __builtin_fmaf(-2.0f, __builtin_amdgcn_rcpf(1.0f + a), 1.0f);
}

// LDS-only barrier: s_waitcnt lgkmcnt(0) + s_barrier. 0xc07f = vmcnt(63)
// expcnt(7) lgkmcnt(0). Keeps global stores / xp prefetch in flight.
__device__ __forceinline__ void lds_barrier() {
    __builtin_amdgcn_s_waitcnt(0xc07f);
    __builtin_amdgcn_s_barrier();
}

// ---------------------------------------------------------------------------
// Kernel 1: x_proj[s][b][n] = input[s][b][:] . W_ih[n][:] + b_ih[n] + b_hh[n]
// stored as bf16 bits. Grid: 2048 blocks x 256 thr; 64 M-rows/block.
// (unchanged this round -- isolating the rnn restructure)
// ---------------------------------------------------------------------------
__global__ __launch_bounds__(256, 2) void proj_kernel(
    const float* __restrict__ inp, const float* __restrict__ W_ih,
    const float* __restrict__ b_ih, const float* __restrict__ b_hh,
    unsigned short* __restrict__ xp)
{
    const int tid  = threadIdx.x;
    const int w    = tid >> 6;
    const int lane = tid & 63;
    const int c    = lane & 15;
    const int q    = lane >> 4;
    const size_t R0 = (size_t)blockIdx.x * 64;

    short8 bfr[4][8];
    float bias[4];
    #pragma unroll
    for (int tn = 0; tn < 4; ++tn) {
        const int n = 64 * w + 16 * tn + c;
        bias[tn] = b_ih[n] + b_hh[n];
        #pragma unroll
        for (int kk = 0; kk < 8; ++kk) {
            const float* p = W_ih + (size_t)n * 256 + kk * 32 + q * 8;
            bfr[tn][kk] = pack8(*(const floatx4*)p, *(const floatx4*)(p + 4));
        }
    }

    #pragma unroll
    for (int mt = 0; mt < 4; ++mt) {
        short8 afr[8];
        const float* arow = inp + (R0 + 16 * mt + c) * 256;
        #pragma unroll
        for (int kk = 0; kk < 8; ++kk) {
            const float* p = arow + kk * 32 + q * 8;
            afr[kk] = pack8(*(const floatx4*)p, *(const floatx4*)(p + 4));
        }
        floatx4 acc[4];
        #pragma unroll
        for (int tn = 0; tn < 4; ++tn) {
            floatx4 a0; a0[0] = bias[tn]; a0[1] = bias[tn]; a0[2] = bias[tn]; a0[3] = bias[tn];
            acc[tn] = a0;
        }
        #pragma unroll
        for (int kk = 0; kk < 8; ++kk)
            #pragma unroll
            for (int tn = 0; tn < 4; ++tn)
                acc[tn] = __builtin_amdgcn_mfma_f32_16x16x32_bf16(afr[kk], bfr[tn][kk], acc[tn], 0, 0, 0);
        #pragma unroll
        for (int tn = 0; tn < 4; ++tn) {
            const unsigned col = 64 * w + 16 * tn + c;
            #pragma unroll
            for (int r = 0; r < 4; ++r) {
                const size_t row = R0 + 16 * mt + q * 4 + r;
                xp[row * 256 + col] = (unsigned short)bf16r(acc[tn][r]);
            }
        }
    }
}

// ---------------------------------------------------------------------------
// Kernel 2: serial recurrence. 4 blocks x 16 batches, now 8 WAVES/block
// (2 waves/SIMD): wave w owns a 32-wide hidden slice (2 MFMA chains).
// Per-SIMD MFMA work unchanged (2 waves x 16 = 32 MFMAs = ~620 cyc floor);
// per-wave epilogue halves (8 tanh), and the second wave on each SIMD hides
// the first's VALU/trans/LDS latency (m114 co-scheduling). LDS reads double
// (64 b128/step) but LDS is a parallel pipe (~670 cyc) -> co-floor w/ MFMA.
// W_hh slice in registers; h double-buffered in LDS bf16, stride 264 ushort
// (33x 4-dword units: (33c+q)%8 uniform -> conflict-minimal b128 reads).
// ---------------------------------------------------------------------------
__global__ __launch_bounds__(512, 2) void rnn_kernel(
    const float* __restrict__ W_hh,
    const unsigned short* __restrict__ xp,   // bf16 bits [SEQ][NBATCH][HIDN]
    float* __restrict__ out)                 // fp32 [SEQ*NBATCH][HIDN]
{
    __shared__ __align__(16) unsigned short hbuf[2][16 * 264];
    const int tid  = threadIdx.x;
    const int w    = tid >> 6, lane = tid & 63;   // w in [0,8)
    const int c    = lane & 15, q = lane >> 4;
    const int B0   = blockIdx.x * 16;

    // B-frags for this wave's 32 columns: n = 32w + 16*t2 + c, t2 in {0,1}
    short8 bfr[2][8];
    #pragma unroll
    for (int t2 = 0; t2 < 2; ++t2) {
        const int n = 32 * w + 16 * t2 + c;
        #pragma unroll
        for (int kk = 0; kk < 8; ++kk) {
            const float* p = W_hh + (size_t)n * 256 + kk * 32 + q * 8;
            bfr[t2][kk] = pack8(*(const floatx4*)p, *(const floatx4*)(p + 4));
        }
    }

    // h0 = 0
    for (int i = tid; i < 2 * 16 * 264; i += 512) (&hbuf[0][0])[i] = 0;
    __syncthreads();

    // per-lane flat offset into [t][b][n]: b = B0+q*4+r, n = 32w+16*t2+c
    const unsigned lofs = (unsigned)(B0 + q * 4) * 256 + 32 * w + c;
    const unsigned short* xq = xp + lofs;
    float* oq = out + lofs;

    // 2-deep xp prefetch ring; i = r*2 + t2
    unsigned xa[8], xb[8];
    #pragma unroll
    for (int i = 0; i < 8; ++i) {
        const int t2 = i & 1, r = i >> 1;
        xa[i] = xq[r * 256 + t2 * 16];
        xb[i] = xq[16384 + r * 256 + t2 * 16];
    }

    auto step = [&](int t, int sel, unsigned* xv) {
        // A-frags first (only dep: barrier) so LDS latency overlaps VALU below
        short8 afr[8];
        #pragma unroll
        for (int kk = 0; kk < 8; ++kk)
            afr[kk] = *(const short8*)&hbuf[sel][c * 264 + kk * 32 + q * 8];

        // acc init = x_proj (prefetched 2 steps ago; bf16 -> f32 is <<16)
        floatx4 acc[2];
        #pragma unroll
        for (int t2 = 0; t2 < 2; ++t2) {
            floatx4 a0;
            a0[0] = __builtin_bit_cast(float, xv[0 * 2 + t2] << 16);
            a0[1] = __builtin_bit_cast(float, xv[1 * 2 + t2] << 16);
            a0[2] = __builtin_bit_cast(float, xv[2 * 2 + t2] << 16);
            a0[3] = __builtin_bit_cast(float, xv[3 * 2 + t2] << 16);
            acc[t2] = a0;
        }

        // prefetch x_proj for t+2 (clamped; dead-but-in-bounds at the tail)
        {
            const int tp = (t + 2 < SEQ) ? (t + 2) : (SEQ - 1);
            const unsigned short* p = xq + (size_t)tp * 16384;
            #pragma unroll
            for (int i = 0; i < 8; ++i) {
                const int t2 = i & 1, r = i >> 1;
                xv[i] = p[r * 256 + t2 * 16];
            }
        }

        // kk-outer: 2 interleaved chains; second wave on the SIMD fills gaps
        #pragma unroll
        for (int kk = 0; kk < 8; ++kk)
            #pragma unroll
            for (int t2 = 0; t2 < 2; ++t2)
                acc[t2] = __builtin_amdgcn_mfma_f32_16x16x32_bf16(afr[kk], bfr[t2][kk], acc[t2], 0, 0, 0);

        // epilogue: tanh, fp32 out store, bf16 h_new into other LDS buffer
        float* op = oq + (size_t)t * 16384;
        unsigned short* hw = &hbuf[sel ^ 1][0];
        #pragma unroll
        for (int t2 = 0; t2 < 2; ++t2) {
            #pragma unroll
            for (int r = 0; r < 4; ++r) {
                const float hn = tanh_fast(acc[t2][r]);
                op[r * 256 + t2 * 16] = hn;
                hw[(q * 4 + r) * 264 + 32 * w + 16 * t2 + c] = (unsigned short)bf16r(hn);
            }
        }
        lds_barrier();
    };

    for (int t = 0; t < SEQ; t += 2) {
        step(t, 0, xa);
        step(t + 1, 1, xb);
    }
}

extern "C" void kernel_launch(void* const* d_in, const int* in_sizes, int n_in,
                              void* d_out, int out_size, void* d_ws, size_t ws_size,
                              hipStream_t stream) {
    const float* input = (const float*)d_in[0];
    const float* W_ih  = (const float*)d_in[1];
    const float* W_hh  = (const float*)d_in[2];
    const float* b_ih  = (const float*)d_in[3];
    const float* b_hh  = (const float*)d_in[4];
    float* out = (float*)d_out;
    unsigned short* xp = (unsigned short*)d_ws;  // 2048*64*256 bf16 = 64 MiB

    proj_kernel<<<(SEQ * NBATCH) / 64, 256, 0, stream>>>(input, W_ih, b_ih, b_hh, xp);
    rnn_kernel<<<4, 512, 0, stream>>>(W_hh, xp, out);
}